// Round 4
// baseline (547.554 us; speedup 1.0000x reference)
//
#include <hip/hip_runtime.h>
#include <math.h>

// Problem constants
#define NN 100000
#define DD 128
#define EE 600000
#define RR 5
#define MCNT (RR * NN)          // 500000 sort buckets
#define NB1 489                 // ceil(MCNT / 1024)

#define WSTR 136                // padded slot stride (f16) for transposed W
#define SLAB 32                 // rows per GEMM slab; 100000 = 3125*32
#define NSLAB (NN / SLAB)
#define ASTR 132                // x-tile stride in agg kernel (pad 4)
#define GBSTR 264               // gamma/beta LDS stride (256 + 8 pad)
#define NTILE (NN / 16)         // 6250 dst tiles

typedef _Float16 v8h __attribute__((ext_vector_type(8)));
typedef _Float16 h4  __attribute__((ext_vector_type(4)));
typedef float    v4f __attribute__((ext_vector_type(4)));

__device__ __forceinline__ float gelu_exact(float v) {
    return 0.5f * v * (1.0f + erff(v * 0.7071067811865476f));
}

// ---------------------------------------------------------------------------
// x (fp32) -> xh (f16)
// ---------------------------------------------------------------------------
__global__ __launch_bounds__(256)
void convert_x(const float* __restrict__ x, _Float16* __restrict__ xh)
{
    size_t u = (size_t)blockIdx.x * 256 + threadIdx.x;
    const float4 a = *(const float4*)(x + u * 8);
    const float4 b = *(const float4*)(x + u * 8 + 4);
    v8h o;
    o[0] = (_Float16)a.x; o[1] = (_Float16)a.y; o[2] = (_Float16)a.z; o[3] = (_Float16)a.w;
    o[4] = (_Float16)b.x; o[5] = (_Float16)b.y; o[6] = (_Float16)b.z; o[7] = (_Float16)b.w;
    *(v8h*)(xh + u * 8) = o;
}

// ---------------------------------------------------------------------------
// Weight transpose to slot-major f16 [slot][WSTR]; slot = output col.
// Layout in wt:
//   [0      .. 1280)  : rel r at r*256:   s<128 -> films_w[r][k][s] (beta)
//                                          s>=128 -> films_w[r][k][s] (gamma)
//   [1280   .. 1920)  : rel r lin at 1280+r*128: lins_w[r][k][s]
//   [1920   .. 2304)  : skip set, 384 slots: s=half*192+a*64+c, col=half*64+c
//                       a=0 lin_skip, a=1 beta(film_skip), a=2 gamma
//   [2304   .. 2432)  : linear1_w cols
// ---------------------------------------------------------------------------
__global__ __launch_bounds__(128)
void transpose_w(const float* __restrict__ lin_skip_w,
                 const float* __restrict__ film_skip_w,
                 const float* __restrict__ lins_w,
                 const float* __restrict__ films_w,
                 const float* __restrict__ linear1_w,
                 _Float16* __restrict__ wt)
{
    const int b = blockIdx.x;
    const int k = threadIdx.x;
    float v;
    if (b < 1280) {
        const int r = b / 256, s = b % 256;
        v = films_w[((size_t)r * DD + k) * 2 * DD + s];
    } else if (b < 1920) {
        const int i = b - 1280, r = i / 128, s = i % 128;
        v = lins_w[((size_t)r * DD + k) * DD + s];
    } else if (b < 2304) {
        const int i = b - 1920;
        const int half = i / 192, rem = i % 192, a = rem / 64;
        const int col = half * 64 + (rem % 64);
        v = (a == 0) ? lin_skip_w[k * DD + col]
          : (a == 1) ? film_skip_w[k * 2 * DD + col]
                     : film_skip_w[k * 2 * DD + DD + col];
    } else {
        v = linear1_w[k * DD + (b - 2304)];
    }
    wt[(size_t)b * WSTR + k] = (_Float16)v;
}

// ---------------------------------------------------------------------------
// Counting sort of edges by key = rel*NN + dst.
// ---------------------------------------------------------------------------
__global__ __launch_bounds__(256)
void count_kernel(const int* __restrict__ ei, const int* __restrict__ et,
                  int* __restrict__ cnt)
{
    int e = blockIdx.x * 256 + threadIdx.x;
    if (e < EE) atomicAdd(&cnt[(size_t)et[e] * NN + ei[EE + e]], 1);
}

__global__ __launch_bounds__(256)
void scan1(const int* __restrict__ cnt, int* __restrict__ partial,
           int* __restrict__ bsum)
{
    __shared__ int s[256];
    const int t = threadIdx.x;
    const int base = blockIdx.x * 1024 + t * 4;
    int v[4], sum = 0;
    #pragma unroll
    for (int j = 0; j < 4; ++j) {
        v[j] = (base + j < MCNT) ? cnt[base + j] : 0;
        sum += v[j];
    }
    s[t] = sum;
    __syncthreads();
    for (int off = 1; off < 256; off <<= 1) {
        int x = (t >= off) ? s[t - off] : 0;
        __syncthreads();
        s[t] += x;
        __syncthreads();
    }
    int run = s[t] - sum;
    if (t == 255) bsum[blockIdx.x] = s[255];
    #pragma unroll
    for (int j = 0; j < 4; ++j) {
        if (base + j < MCNT) partial[base + j] = run;
        run += v[j];
    }
}

__global__ __launch_bounds__(512)
void scan2(const int* __restrict__ bsum, int* __restrict__ bsum2)
{
    __shared__ int s[512];
    const int t = threadIdx.x;
    const int v = (t < NB1) ? bsum[t] : 0;
    s[t] = v;
    __syncthreads();
    for (int off = 1; off < 512; off <<= 1) {
        int x = (t >= off) ? s[t - off] : 0;
        __syncthreads();
        s[t] += x;
        __syncthreads();
    }
    if (t < NB1) bsum2[t] = s[t] - v;
}

__global__ __launch_bounds__(256)
void scan3(const int* __restrict__ partial, const int* __restrict__ bsum2,
           int* __restrict__ rowptr, int* __restrict__ head)
{
    const int t = threadIdx.x;
    const int base = blockIdx.x * 1024 + t * 4;
    const int add = bsum2[blockIdx.x];
    #pragma unroll
    for (int j = 0; j < 4; ++j) {
        if (base + j < MCNT) {
            int v = partial[base + j] + add;
            rowptr[base + j] = v;
            head[base + j]   = v;
        }
    }
    if (blockIdx.x == 0 && t == 0) rowptr[MCNT] = EE;
}

__global__ __launch_bounds__(256)
void scatter_kernel(const int* __restrict__ ei, const int* __restrict__ et,
                    int* __restrict__ head, int* __restrict__ srcs)
{
    int e = blockIdx.x * 256 + threadIdx.x;
    if (e < EE) {
        int pos = atomicAdd(&head[(size_t)et[e] * NN + ei[EE + e]], 1);
        srcs[pos] = ei[e];
    }
}

// ---------------------------------------------------------------------------
// Skip path: out_acc = relu(gamma_s * (x@lin_skip) + beta_s), f16 output.
// W-stationary (384 slots in 2 halves), persistent blocks.
// ---------------------------------------------------------------------------
#define HALF_SLOTS 192
__global__ __launch_bounds__(256)
void skip_mfma(const _Float16* __restrict__ xh,
               const _Float16* __restrict__ Wt,     // wt + 1920*WSTR
               _Float16* __restrict__ oa)
{
    __shared__ _Float16 Wl[HALF_SLOTS * WSTR];
    __shared__ _Float16 Al[SLAB * WSTR];
    const int tid  = threadIdx.x;
    const int wv   = tid >> 6;
    const int lane = tid & 63;
    const int l15  = lane & 15;
    const int quad = lane >> 4;

    for (int half = 0; half < 2; ++half) {
        __syncthreads();
        for (int u = tid; u < (HALF_SLOTS * WSTR) / 8; u += 256)
            *(v8h*)(Wl + (size_t)u * 8) =
                *(const v8h*)(Wt + (size_t)half * HALF_SLOTS * WSTR + (size_t)u * 8);

        const int c0 = half * 64 + wv * 16 + quad * 4;

        for (int s = blockIdx.x; s < NSLAB; s += gridDim.x) {
            __syncthreads();
            #pragma unroll
            for (int j = 0; j < 2; ++j) {
                int u = tid + j * 256;
                int row = u >> 4, c8 = u & 15;
                *(v8h*)(Al + row * WSTR + c8 * 8) =
                    *(const v8h*)(xh + ((size_t)s * SLAB + row) * DD + c8 * 8);
            }
            __syncthreads();

            v4f acc[3][2];
            #pragma unroll
            for (int a = 0; a < 3; ++a)
                #pragma unroll
                for (int rt = 0; rt < 2; ++rt)
                    acc[a][rt] = (v4f){0.f, 0.f, 0.f, 0.f};

            #pragma unroll
            for (int ks = 0; ks < 4; ++ks) {
                v8h xf0 = *(v8h*)(Al + l15 * WSTR + ks * 32 + quad * 8);
                v8h xf1 = *(v8h*)(Al + (16 + l15) * WSTR + ks * 32 + quad * 8);
                v8h wf[3];
                #pragma unroll
                for (int a = 0; a < 3; ++a)
                    wf[a] = *(v8h*)(Wl + (a * 64 + wv * 16 + l15) * WSTR + ks * 32 + quad * 8);
                #pragma unroll
                for (int a = 0; a < 3; ++a) {
                    acc[a][0] = __builtin_amdgcn_mfma_f32_16x16x32_f16(wf[a], xf0, acc[a][0], 0, 0, 0);
                    acc[a][1] = __builtin_amdgcn_mfma_f32_16x16x32_f16(wf[a], xf1, acc[a][1], 0, 0, 0);
                }
            }

            #pragma unroll
            for (int rt = 0; rt < 2; ++rt) {
                const size_t row = (size_t)s * SLAB + rt * 16 + l15;
                v4f xv = acc[0][rt], bv = acc[1][rt], gv = acc[2][rt];
                h4 o;
                o[0] = (_Float16)fmaxf(gv[0] * xv[0] + bv[0], 0.f);
                o[1] = (_Float16)fmaxf(gv[1] * xv[1] + bv[1], 0.f);
                o[2] = (_Float16)fmaxf(gv[2] * xv[2] + bv[2], 0.f);
                o[3] = (_Float16)fmaxf(gv[3] * xv[3] + bv[3], 0.f);
                *(h4*)(oa + row * DD + c0) = o;
            }
        }
    }
}

// ---------------------------------------------------------------------------
// xl = x @ lins_w[r], f16 output. W-stationary (128 slots), persistent.
// ---------------------------------------------------------------------------
__global__ __launch_bounds__(256)
void lin_mfma(const _Float16* __restrict__ xh,
              const _Float16* __restrict__ Wt,      // [128][WSTR]
              _Float16* __restrict__ xl)
{
    __shared__ _Float16 Wl[DD * WSTR];
    __shared__ _Float16 Al[SLAB * WSTR];
    const int tid  = threadIdx.x;
    const int wv   = tid >> 6;
    const int lane = tid & 63;
    const int l15  = lane & 15;
    const int quad = lane >> 4;

    for (int u = tid; u < (DD * WSTR) / 8; u += 256)
        *(v8h*)(Wl + (size_t)u * 8) = *(const v8h*)(Wt + (size_t)u * 8);

    for (int s = blockIdx.x; s < NSLAB; s += gridDim.x) {
        __syncthreads();
        #pragma unroll
        for (int j = 0; j < 2; ++j) {
            int u = tid + j * 256;
            int row = u >> 4, c8 = u & 15;
            *(v8h*)(Al + row * WSTR + c8 * 8) =
                *(const v8h*)(xh + ((size_t)s * SLAB + row) * DD + c8 * 8);
        }
        __syncthreads();

        v4f acc[2][2];
        #pragma unroll
        for (int ct = 0; ct < 2; ++ct)
            #pragma unroll
            for (int rt = 0; rt < 2; ++rt)
                acc[ct][rt] = (v4f){0.f, 0.f, 0.f, 0.f};

        #pragma unroll
        for (int ks = 0; ks < 4; ++ks) {
            v8h xf0 = *(v8h*)(Al + l15 * WSTR + ks * 32 + quad * 8);
            v8h xf1 = *(v8h*)(Al + (16 + l15) * WSTR + ks * 32 + quad * 8);
            v8h wf[2];
            #pragma unroll
            for (int ct = 0; ct < 2; ++ct)
                wf[ct] = *(v8h*)(Wl + (wv * 32 + ct * 16 + l15) * WSTR + ks * 32 + quad * 8);
            #pragma unroll
            for (int ct = 0; ct < 2; ++ct) {
                acc[ct][0] = __builtin_amdgcn_mfma_f32_16x16x32_f16(wf[ct], xf0, acc[ct][0], 0, 0, 0);
                acc[ct][1] = __builtin_amdgcn_mfma_f32_16x16x32_f16(wf[ct], xf1, acc[ct][1], 0, 0, 0);
            }
        }

        #pragma unroll
        for (int ct = 0; ct < 2; ++ct)
            #pragma unroll
            for (int rt = 0; rt < 2; ++rt) {
                const size_t row = (size_t)s * SLAB + rt * 16 + l15;
                const int c0 = wv * 32 + ct * 16 + quad * 4;
                h4 o;
                o[0] = (_Float16)acc[ct][rt][0];
                o[1] = (_Float16)acc[ct][rt][1];
                o[2] = (_Float16)acc[ct][rt][2];
                o[3] = (_Float16)acc[ct][rt][3];
                *(h4*)(xl + row * DD + c0) = o;
            }
    }
}

// ---------------------------------------------------------------------------
// Fused aggregation for one relation. Per 16-dst tile:
//   1. MFMA computes gamma/beta for the 16 dsts (W in registers, x from LDS)
//   2. transpose gamma/beta into LDS (+bias)
//   3. 16-lane group per dst: gather xl[src] over CSR bucket, accumulate
//      relu(g*x+b), single f16 RMW of out_acc (owner-computes, no atomics).
// gamma/beta never touch global memory.
// ---------------------------------------------------------------------------
__global__ __launch_bounds__(256)
void agg_fused(const int* __restrict__ rowptr_rel,   // rowptr + rel*NN
               const int* __restrict__ srcs,
               const _Float16* __restrict__ xh,
               const _Float16* __restrict__ Wt,      // wt + rel*256*WSTR
               const float* __restrict__ bias,       // films_b + rel*256
               const _Float16* __restrict__ xl,
               _Float16* __restrict__ oa)
{
    __shared__ _Float16 As[16 * ASTR];
    __shared__ _Float16 gb[16 * GBSTR];   // [dst][col]: 0-127 beta, 128-255 gamma
    const int tid  = threadIdx.x;
    const int wv   = tid >> 6;
    const int lane = tid & 63;
    const int l15  = lane & 15;
    const int quad = lane >> 4;

    // W fragments in registers: wave wv owns output cols [wv*64, wv*64+64)
    v8h wf[4][4];
    #pragma unroll
    for (int m = 0; m < 4; ++m)
        #pragma unroll
        for (int ks = 0; ks < 4; ++ks)
            wf[m][ks] = *(const v8h*)(Wt + (size_t)((wv * 4 + m) * 16 + l15) * WSTR
                                      + ks * 32 + quad * 8);
    float4 bfr[4];
    #pragma unroll
    for (int m = 0; m < 4; ++m)
        bfr[m] = *(const float4*)(bias + (wv * 4 + m) * 16 + quad * 4);

    const int g  = tid >> 4;          // edge-phase dst-in-tile
    const int c0 = (tid & 15) * 8;    // edge-phase col base

    for (int tile = blockIdx.x; tile < NTILE; tile += gridDim.x) {
        __syncthreads();              // prior tile's As/gb reads complete
        // stage 16 consecutive x rows (one v8h per thread)
        {
            const int row = tid >> 4, c8 = tid & 15;
            *(v8h*)(As + row * ASTR + c8 * 8) =
                *(const v8h*)(xh + ((size_t)tile * 16 + row) * DD + c8 * 8);
        }
        __syncthreads();

        v4f acc[4];
        #pragma unroll
        for (int m = 0; m < 4; ++m) acc[m] = (v4f){0.f, 0.f, 0.f, 0.f};
        #pragma unroll
        for (int ks = 0; ks < 4; ++ks) {
            v8h xf = *(v8h*)(As + l15 * ASTR + ks * 32 + quad * 8);
            #pragma unroll
            for (int m = 0; m < 4; ++m)
                acc[m] = __builtin_amdgcn_mfma_f32_16x16x32_f16(wf[m][ks], xf, acc[m], 0, 0, 0);
        }
        // transpose to gb: lane holds dst=l15, cols (wv*4+m)*16 + quad*4 + r
        #pragma unroll
        for (int m = 0; m < 4; ++m) {
            h4 o;
            o[0] = (_Float16)(acc[m][0] + bfr[m].x);
            o[1] = (_Float16)(acc[m][1] + bfr[m].y);
            o[2] = (_Float16)(acc[m][2] + bfr[m].z);
            o[3] = (_Float16)(acc[m][3] + bfr[m].w);
            *(h4*)(gb + l15 * GBSTR + (wv * 4 + m) * 16 + quad * 4) = o;
        }
        __syncthreads();

        // edge phase
        const int d     = tile * 16 + g;
        const int start = rowptr_rel[d];
        const int end   = rowptr_rel[d + 1];
        if (start < end) {
            const v8h bb = *(v8h*)(gb + g * GBSTR + c0);
            const v8h gg = *(v8h*)(gb + g * GBSTR + DD + c0);
            float a[8] = {0.f, 0.f, 0.f, 0.f, 0.f, 0.f, 0.f, 0.f};
            for (int p = start; p < end; ++p) {
                const int s = srcs[p];
                const v8h xs = *(const v8h*)(xl + (size_t)s * DD + c0);
                #pragma unroll
                for (int j = 0; j < 8; ++j)
                    a[j] += fmaxf((float)gg[j] * (float)xs[j] + (float)bb[j], 0.f);
            }
            const float inv = 1.0f / (float)(end - start);
            _Float16* dp = oa + (size_t)d * DD + c0;
            v8h old = *(v8h*)dp;
            v8h nw;
            #pragma unroll
            for (int j = 0; j < 8; ++j)
                nw[j] = (_Float16)((float)old[j] + a[j] * inv);
            *(v8h*)dp = nw;
        }
    }
}

// ---------------------------------------------------------------------------
// out = gelu(out_acc) @ linear1_w + linear1_b   (f16 input, fp32 output)
// ---------------------------------------------------------------------------
__global__ __launch_bounds__(256)
void final_mfma(const _Float16* __restrict__ oa,
                const _Float16* __restrict__ Wt,    // wt + 2304*WSTR
                const float* __restrict__ bias,
                float* __restrict__ out)
{
    __shared__ _Float16 Wl[DD * WSTR];
    __shared__ _Float16 Al[SLAB * WSTR];
    const int tid  = threadIdx.x;
    const int wv   = tid >> 6;
    const int lane = tid & 63;
    const int l15  = lane & 15;
    const int quad = lane >> 4;

    for (int u = tid; u < (DD * WSTR) / 8; u += 256)
        *(v8h*)(Wl + (size_t)u * 8) = *(const v8h*)(Wt + (size_t)u * 8);

    float4 bf[2];
    #pragma unroll
    for (int ct = 0; ct < 2; ++ct)
        bf[ct] = *(const float4*)(bias + wv * 32 + ct * 16 + quad * 4);

    for (int s = blockIdx.x; s < NSLAB; s += gridDim.x) {
        __syncthreads();
        #pragma unroll
        for (int j = 0; j < 2; ++j) {
            int u = tid + j * 256;
            int row = u >> 4, c8 = (u & 15) * 8;
            v8h g = *(const v8h*)(oa + ((size_t)s * SLAB + row) * DD + c8);
            v8h o;
            #pragma unroll
            for (int q = 0; q < 8; ++q)
                o[q] = (_Float16)gelu_exact((float)g[q]);
            *(v8h*)(Al + row * WSTR + c8) = o;
        }
        __syncthreads();

        v4f acc[2][2];
        #pragma unroll
        for (int ct = 0; ct < 2; ++ct)
            #pragma unroll
            for (int rt = 0; rt < 2; ++rt)
                acc[ct][rt] = (v4f){0.f, 0.f, 0.f, 0.f};

        #pragma unroll
        for (int ks = 0; ks < 4; ++ks) {
            v8h xf0 = *(v8h*)(Al + l15 * WSTR + ks * 32 + quad * 8);
            v8h xf1 = *(v8h*)(Al + (16 + l15) * WSTR + ks * 32 + quad * 8);
            v8h wf[2];
            #pragma unroll
            for (int ct = 0; ct < 2; ++ct)
                wf[ct] = *(v8h*)(Wl + (wv * 32 + ct * 16 + l15) * WSTR + ks * 32 + quad * 8);
            #pragma unroll
            for (int ct = 0; ct < 2; ++ct) {
                acc[ct][0] = __builtin_amdgcn_mfma_f32_16x16x32_f16(wf[ct], xf0, acc[ct][0], 0, 0, 0);
                acc[ct][1] = __builtin_amdgcn_mfma_f32_16x16x32_f16(wf[ct], xf1, acc[ct][1], 0, 0, 0);
            }
        }

        #pragma unroll
        for (int ct = 0; ct < 2; ++ct)
            #pragma unroll
            for (int rt = 0; rt < 2; ++rt) {
                const size_t row = (size_t)s * SLAB + rt * 16 + l15;
                const int c0 = wv * 32 + ct * 16 + quad * 4;
                float4 o;
                o.x = acc[ct][rt][0] + bf[ct].x;
                o.y = acc[ct][rt][1] + bf[ct].y;
                o.z = acc[ct][rt][2] + bf[ct].z;
                o.w = acc[ct][rt][3] + bf[ct].w;
                *(float4*)(out + row * DD + c0) = o;
            }
    }
}

extern "C" void kernel_launch(void* const* d_in, const int* in_sizes, int n_in,
                              void* d_out, int out_size, void* d_ws, size_t ws_size,
                              hipStream_t stream)
{
    const float* x           = (const float*)d_in[0];
    const int*   ei          = (const int*)d_in[1];
    const int*   et          = (const int*)d_in[2];
    const float* lin_skip_w  = (const float*)d_in[3];
    const float* film_skip_w = (const float*)d_in[4];
    const float* lins_w      = (const float*)d_in[5];
    const float* films_w     = (const float*)d_in[6];
    const float* films_b     = (const float*)d_in[7];
    const float* linear1_w   = (const float*)d_in[8];
    const float* linear1_b   = (const float*)d_in[9];
    float* out = (float*)d_out;
    char*  ws  = (char*)d_ws;

    // workspace layout (bytes, 256-aligned)
    _Float16* xh      = (_Float16*)(ws);                   // 25,600,000
    _Float16* wt      = (_Float16*)(ws + 25600000);        //    661,504
    _Float16* xl      = (_Float16*)(ws + 26261504);        // 25,600,000
    _Float16* oa      = (_Float16*)(ws + 51861504);        // 25,600,000
    int*      cnt     = (int*)     (ws + 77461504);        //  2,000,000
    int*      partial = (int*)     (ws + 79461504);        //  2,000,000
    int*      rowptr  = (int*)     (ws + 81461504);        //  2,000,128
    int*      head    = (int*)     (ws + 83461632);        //  2,000,000
    int*      srcs    = (int*)     (ws + 85461632);        //  2,400,000
    int*      bsum    = (int*)     (ws + 87861632);        //      4,096
    int*      bsum2   = (int*)     (ws + 87865728);        //      4,096

    convert_x<<<6250, 256, 0, stream>>>(x, xh);
    transpose_w<<<2432, 128, 0, stream>>>(lin_skip_w, film_skip_w,
                                          lins_w, films_w, linear1_w, wt);

    // counting sort of edges by (rel, dst)
    hipMemsetAsync(cnt, 0, (size_t)MCNT * sizeof(int), stream);
    count_kernel<<<(EE + 255) / 256, 256, 0, stream>>>(ei, et, cnt);
    scan1<<<NB1, 256, 0, stream>>>(cnt, partial, bsum);
    scan2<<<1, 512, 0, stream>>>(bsum, bsum2);
    scan3<<<NB1, 256, 0, stream>>>(partial, bsum2, rowptr, head);
    scatter_kernel<<<(EE + 255) / 256, 256, 0, stream>>>(ei, et, head, srcs);

    // skip path -> out_acc (f16)
    skip_mfma<<<512, 256, 0, stream>>>(xh, wt + (size_t)1920 * WSTR, oa);

    for (int r = 0; r < RR; ++r) {
        lin_mfma<<<512, 256, 0, stream>>>(xh, wt + (size_t)(1280 + r * 128) * WSTR, xl);
        agg_fused<<<1024, 256, 0, stream>>>(rowptr + (size_t)r * NN, srcs, xh,
                                            wt + (size_t)r * 256 * WSTR,
                                            films_b + (size_t)r * 2 * DD,
                                            xl, oa);
    }

    final_mfma<<<512, 256, 0, stream>>>(oa, wt + (size_t)2304 * WSTR,
                                        linear1_b, out);
}

// Round 5
// 497.061 us; speedup vs baseline: 1.1016x; 1.1016x over previous
//
#include <hip/hip_runtime.h>
#include <math.h>

// Problem constants
#define NN 100000
#define DD 128
#define EE 600000
#define RR 5
#define MCNT (RR * NN)          // 500000 sort buckets
#define NB1 489                 // ceil(MCNT / 1024)

#define WSTR 136                // padded slot stride (f16) for transposed W
#define HALF_SLOTS 192
#define SLAB 32                 // rows per GEMM slab; 100000 = 3125*32
#define NSLAB (NN / SLAB)

// prep kernel partitions
#define CONV_BLKS 6250
#define ZERO_BLKS 245           // 245*2048 >= 500000
#define TW_BLKS  1216           // 1216*2 = 2432 weight slots

typedef _Float16 v8h __attribute__((ext_vector_type(8)));
typedef _Float16 h4  __attribute__((ext_vector_type(4)));
typedef float    v4f __attribute__((ext_vector_type(4)));

__device__ __forceinline__ float gelu_exact(float v) {
    return 0.5f * v * (1.0f + erff(v * 0.7071067811865476f));
}

// ---------------------------------------------------------------------------
// prep: fused convert_x (f32->f16) + cnt zero + weight transpose.
// Weight layout in wt (slot-major, stride WSTR, slot = output col):
//   set 0 = skip at 0, sets 1..5 = rels at set*384: s = half*192 + a*64 + c
//     a=0 -> lin col (half*64+c); a=1 -> beta col; a=2 -> gamma col
//   linear1_w cols at slot 2304..2432
// ---------------------------------------------------------------------------
__global__ __launch_bounds__(256)
void prep(const float* __restrict__ x, _Float16* __restrict__ xh,
          int* __restrict__ cnt,
          const float* __restrict__ lin_skip_w,
          const float* __restrict__ film_skip_w,
          const float* __restrict__ lins_w,
          const float* __restrict__ films_w,
          const float* __restrict__ linear1_w,
          _Float16* __restrict__ wt)
{
    const int b = blockIdx.x;
    if (b < CONV_BLKS) {
        size_t u = (size_t)b * 256 + threadIdx.x;
        const float4 a = *(const float4*)(x + u * 8);
        const float4 c = *(const float4*)(x + u * 8 + 4);
        v8h o;
        o[0] = (_Float16)a.x; o[1] = (_Float16)a.y; o[2] = (_Float16)a.z; o[3] = (_Float16)a.w;
        o[4] = (_Float16)c.x; o[5] = (_Float16)c.y; o[6] = (_Float16)c.z; o[7] = (_Float16)c.w;
        *(v8h*)(xh + u * 8) = o;
    } else if (b < CONV_BLKS + ZERO_BLKS) {
        int i = (b - CONV_BLKS) * 2048 + threadIdx.x * 8;
        #pragma unroll
        for (int j = 0; j < 8; ++j)
            if (i + j < MCNT) cnt[i + j] = 0;
    } else {
        const int bb = (b - CONV_BLKS - ZERO_BLKS) * 2 + (threadIdx.x >> 7);
        const int k  = threadIdx.x & 127;
        float v;
        _Float16* dst;
        if (bb < 6 * 384) {
            const int set = bb / 384;
            const int s   = bb % 384;
            const int half = s / 192;
            const int rem  = s % 192;
            const int a    = rem / 64;
            const int col  = half * 64 + (rem % 64);
            if (set == 0) {
                v = (a == 0) ? lin_skip_w[k * DD + col]
                             : film_skip_w[k * 2 * DD + (a - 1) * DD + col];
            } else {
                const int r = set - 1;
                v = (a == 0) ? lins_w[((size_t)r * DD + k) * DD + col]
                             : films_w[((size_t)r * DD + k) * 2 * DD + (a - 1) * DD + col];
            }
            dst = wt + (size_t)set * 384 * WSTR + (size_t)s * WSTR + k;
        } else {
            const int s = bb - 2304;
            v = linear1_w[k * DD + s];
            dst = wt + (size_t)2304 * WSTR + (size_t)s * WSTR + k;
        }
        *dst = (_Float16)v;
    }
}

// ---------------------------------------------------------------------------
// Counting sort of edges by key = rel*NN + dst.
// ---------------------------------------------------------------------------
__global__ __launch_bounds__(256)
void count_kernel(const int* __restrict__ ei, const int* __restrict__ et,
                  int* __restrict__ cnt)
{
    int e = blockIdx.x * 256 + threadIdx.x;
    if (e < EE) atomicAdd(&cnt[(size_t)et[e] * NN + ei[EE + e]], 1);
}

__global__ __launch_bounds__(256)
void scan1(const int* __restrict__ cnt, int* __restrict__ partial,
           int* __restrict__ bsum)
{
    __shared__ int s[256];
    const int t = threadIdx.x;
    const int base = blockIdx.x * 1024 + t * 4;
    int v[4], sum = 0;
    #pragma unroll
    for (int j = 0; j < 4; ++j) {
        v[j] = (base + j < MCNT) ? cnt[base + j] : 0;
        sum += v[j];
    }
    s[t] = sum;
    __syncthreads();
    for (int off = 1; off < 256; off <<= 1) {
        int x = (t >= off) ? s[t - off] : 0;
        __syncthreads();
        s[t] += x;
        __syncthreads();
    }
    int run = s[t] - sum;
    if (t == 255) bsum[blockIdx.x] = s[255];
    #pragma unroll
    for (int j = 0; j < 4; ++j) {
        if (base + j < MCNT) partial[base + j] = run;
        run += v[j];
    }
}

__global__ __launch_bounds__(512)
void scan2(const int* __restrict__ bsum, int* __restrict__ bsum2)
{
    __shared__ int s[512];
    const int t = threadIdx.x;
    const int v = (t < NB1) ? bsum[t] : 0;
    s[t] = v;
    __syncthreads();
    for (int off = 1; off < 512; off <<= 1) {
        int x = (t >= off) ? s[t - off] : 0;
        __syncthreads();
        s[t] += x;
        __syncthreads();
    }
    if (t < NB1) bsum2[t] = s[t] - v;
}

__global__ __launch_bounds__(256)
void scan3(const int* __restrict__ partial, const int* __restrict__ bsum2,
           int* __restrict__ rowptr, int* __restrict__ head)
{
    const int t = threadIdx.x;
    const int base = blockIdx.x * 1024 + t * 4;
    const int add = bsum2[blockIdx.x];
    #pragma unroll
    for (int j = 0; j < 4; ++j) {
        if (base + j < MCNT) {
            int v = partial[base + j] + add;
            rowptr[base + j] = v;
            head[base + j]   = v;
        }
    }
    if (blockIdx.x == 0 && t == 0) rowptr[MCNT] = EE;
}

__global__ __launch_bounds__(256)
void scatter_kernel(const int* __restrict__ ei, const int* __restrict__ et,
                    int* __restrict__ head, int* __restrict__ srcs)
{
    int e = blockIdx.x * 256 + threadIdx.x;
    if (e < EE) {
        int pos = atomicAdd(&head[(size_t)et[e] * NN + ei[EE + e]], 1);
        srcs[pos] = ei[e];
    }
}

// ---------------------------------------------------------------------------
// Skip path: oa = relu(gamma_s * (x@lin_skip) + beta_s), f16 out.
// ---------------------------------------------------------------------------
__global__ __launch_bounds__(256)
void skip_mfma(const _Float16* __restrict__ xh,
               const _Float16* __restrict__ Wt,     // wt + 0 (set 0)
               _Float16* __restrict__ oa)
{
    __shared__ _Float16 Wl[HALF_SLOTS * WSTR];
    __shared__ _Float16 Al[SLAB * WSTR];
    const int tid  = threadIdx.x;
    const int wv   = tid >> 6;
    const int lane = tid & 63;
    const int l15  = lane & 15;
    const int quad = lane >> 4;

    for (int half = 0; half < 2; ++half) {
        __syncthreads();
        for (int u = tid; u < (HALF_SLOTS * WSTR) / 8; u += 256)
            *(v8h*)(Wl + (size_t)u * 8) =
                *(const v8h*)(Wt + (size_t)half * HALF_SLOTS * WSTR + (size_t)u * 8);

        const int c0 = half * 64 + wv * 16 + quad * 4;

        for (int s = blockIdx.x; s < NSLAB; s += gridDim.x) {
            __syncthreads();
            #pragma unroll
            for (int j = 0; j < 2; ++j) {
                int u = tid + j * 256;
                int row = u >> 4, c8 = u & 15;
                *(v8h*)(Al + row * WSTR + c8 * 8) =
                    *(const v8h*)(xh + ((size_t)s * SLAB + row) * DD + c8 * 8);
            }
            __syncthreads();

            v4f acc[3][2];
            #pragma unroll
            for (int a = 0; a < 3; ++a)
                #pragma unroll
                for (int rt = 0; rt < 2; ++rt)
                    acc[a][rt] = (v4f){0.f, 0.f, 0.f, 0.f};

            #pragma unroll
            for (int ks = 0; ks < 4; ++ks) {
                v8h xf0 = *(v8h*)(Al + l15 * WSTR + ks * 32 + quad * 8);
                v8h xf1 = *(v8h*)(Al + (16 + l15) * WSTR + ks * 32 + quad * 8);
                v8h wf[3];
                #pragma unroll
                for (int a = 0; a < 3; ++a)
                    wf[a] = *(v8h*)(Wl + (a * 64 + wv * 16 + l15) * WSTR + ks * 32 + quad * 8);
                #pragma unroll
                for (int a = 0; a < 3; ++a) {
                    acc[a][0] = __builtin_amdgcn_mfma_f32_16x16x32_f16(wf[a], xf0, acc[a][0], 0, 0, 0);
                    acc[a][1] = __builtin_amdgcn_mfma_f32_16x16x32_f16(wf[a], xf1, acc[a][1], 0, 0, 0);
                }
            }

            #pragma unroll
            for (int rt = 0; rt < 2; ++rt) {
                const size_t row = (size_t)s * SLAB + rt * 16 + l15;
                v4f xv = acc[0][rt], bv = acc[1][rt], gv = acc[2][rt];
                h4 o;
                o[0] = (_Float16)fmaxf(gv[0] * xv[0] + bv[0], 0.f);
                o[1] = (_Float16)fmaxf(gv[1] * xv[1] + bv[1], 0.f);
                o[2] = (_Float16)fmaxf(gv[2] * xv[2] + bv[2], 0.f);
                o[3] = (_Float16)fmaxf(gv[3] * xv[3] + bv[3], 0.f);
                *(h4*)(oa + row * DD + c0) = o;
            }
        }
    }
}

// ---------------------------------------------------------------------------
// film_mfma: per relation, xl = x@lins_w[r]; beta/gamma = x@films_w[r]+bias.
// f16 outputs. W-stationary (384 slots in 2 halves), persistent blocks.
// ---------------------------------------------------------------------------
__global__ __launch_bounds__(256)
void film_mfma(const _Float16* __restrict__ xh,
               const _Float16* __restrict__ Wt,     // wt + (r+1)*384*WSTR
               const float* __restrict__ bias,      // films_b + r*256
               _Float16* __restrict__ xl,
               _Float16* __restrict__ bh,
               _Float16* __restrict__ gh)
{
    __shared__ _Float16 Wl[HALF_SLOTS * WSTR];
    __shared__ _Float16 Al[SLAB * WSTR];
    const int tid  = threadIdx.x;
    const int wv   = tid >> 6;
    const int lane = tid & 63;
    const int l15  = lane & 15;
    const int quad = lane >> 4;

    for (int half = 0; half < 2; ++half) {
        __syncthreads();
        for (int u = tid; u < (HALF_SLOTS * WSTR) / 8; u += 256)
            *(v8h*)(Wl + (size_t)u * 8) =
                *(const v8h*)(Wt + (size_t)half * HALF_SLOTS * WSTR + (size_t)u * 8);

        const int c0 = half * 64 + wv * 16 + quad * 4;
        const float4 bb = *(const float4*)(bias + c0);
        const float4 bg = *(const float4*)(bias + DD + c0);

        for (int s = blockIdx.x; s < NSLAB; s += gridDim.x) {
            __syncthreads();
            #pragma unroll
            for (int j = 0; j < 2; ++j) {
                int u = tid + j * 256;
                int row = u >> 4, c8 = u & 15;
                *(v8h*)(Al + row * WSTR + c8 * 8) =
                    *(const v8h*)(xh + ((size_t)s * SLAB + row) * DD + c8 * 8);
            }
            __syncthreads();

            v4f acc[3][2];
            #pragma unroll
            for (int a = 0; a < 3; ++a)
                #pragma unroll
                for (int rt = 0; rt < 2; ++rt)
                    acc[a][rt] = (v4f){0.f, 0.f, 0.f, 0.f};

            #pragma unroll
            for (int ks = 0; ks < 4; ++ks) {
                v8h xf0 = *(v8h*)(Al + l15 * WSTR + ks * 32 + quad * 8);
                v8h xf1 = *(v8h*)(Al + (16 + l15) * WSTR + ks * 32 + quad * 8);
                v8h wf[3];
                #pragma unroll
                for (int a = 0; a < 3; ++a)
                    wf[a] = *(v8h*)(Wl + (a * 64 + wv * 16 + l15) * WSTR + ks * 32 + quad * 8);
                #pragma unroll
                for (int a = 0; a < 3; ++a) {
                    acc[a][0] = __builtin_amdgcn_mfma_f32_16x16x32_f16(wf[a], xf0, acc[a][0], 0, 0, 0);
                    acc[a][1] = __builtin_amdgcn_mfma_f32_16x16x32_f16(wf[a], xf1, acc[a][1], 0, 0, 0);
                }
            }

            #pragma unroll
            for (int rt = 0; rt < 2; ++rt) {
                const size_t row = (size_t)s * SLAB + rt * 16 + l15;
                v4f xv = acc[0][rt], bv = acc[1][rt], gv = acc[2][rt];
                h4 ox, ob, og;
                ox[0] = (_Float16)xv[0]; ox[1] = (_Float16)xv[1];
                ox[2] = (_Float16)xv[2]; ox[3] = (_Float16)xv[3];
                ob[0] = (_Float16)(bv[0] + bb.x); ob[1] = (_Float16)(bv[1] + bb.y);
                ob[2] = (_Float16)(bv[2] + bb.z); ob[3] = (_Float16)(bv[3] + bb.w);
                og[0] = (_Float16)(gv[0] + bg.x); og[1] = (_Float16)(gv[1] + bg.y);
                og[2] = (_Float16)(gv[2] + bg.z); og[3] = (_Float16)(gv[3] + bg.w);
                *(h4*)(xl + row * DD + c0) = ox;
                *(h4*)(bh + row * DD + c0) = ob;
                *(h4*)(gh + row * DD + c0) = og;
            }
        }
    }
}

// ---------------------------------------------------------------------------
// Owner-computes aggregation, barrier-free, MLP-batched gathers.
// One 16-lane group per dst. All srcs + xl gathers of a batch of 8 edges are
// issued as independent loads (clamped addresses, masked accumulate) so the
// latency chain is ~1 gather deep instead of k deep.
// ---------------------------------------------------------------------------
__global__ __launch_bounds__(256)
void agg_pass(const int* __restrict__ rp,            // rowptr + rel*NN
              const int* __restrict__ srcs,
              const _Float16* __restrict__ xl,
              const _Float16* __restrict__ bh,
              const _Float16* __restrict__ gh,
              _Float16* __restrict__ oa)
{
    const int d  = blockIdx.x * 16 + (threadIdx.x >> 4);
    const int c0 = (threadIdx.x & 15) * 8;
    // issue all independent row-loads up front
    const int start = rp[d];
    const int end   = rp[d + 1];
    const v8h gs = *(const v8h*)(gh + (size_t)d * DD + c0);
    const v8h bs = *(const v8h*)(bh + (size_t)d * DD + c0);
    const int k = end - start;
    if (k <= 0) return;

    float acc[8] = {0.f, 0.f, 0.f, 0.f, 0.f, 0.f, 0.f, 0.f};
    int p = start;
    while (p < end) {
        const int kb = min(end - p, 8);
        int sidx[8];
        #pragma unroll
        for (int j = 0; j < 8; ++j)
            sidx[j] = srcs[p + min(j, kb - 1)];      // clamped: always valid
        v8h xv[8];
        #pragma unroll
        for (int j = 0; j < 8; ++j)
            xv[j] = *(const v8h*)(xl + (size_t)sidx[j] * DD + c0);
        #pragma unroll
        for (int j = 0; j < 8; ++j) {
            if (j < kb) {
                #pragma unroll
                for (int q = 0; q < 8; ++q)
                    acc[q] += fmaxf((float)gs[q] * (float)xv[j][q] + (float)bs[q], 0.f);
            }
        }
        p += kb;
    }

    const float inv = 1.0f / (float)k;
    _Float16* dp = oa + (size_t)d * DD + c0;
    v8h old = *(v8h*)dp;
    v8h nw;
    #pragma unroll
    for (int q = 0; q < 8; ++q)
        nw[q] = (_Float16)((float)old[q] + acc[q] * inv);
    *(v8h*)dp = nw;
}

// ---------------------------------------------------------------------------
// out = gelu(oa) @ linear1_w + linear1_b   (f16 in, fp32 out)
// ---------------------------------------------------------------------------
__global__ __launch_bounds__(256)
void final_mfma(const _Float16* __restrict__ oa,
                const _Float16* __restrict__ Wt,    // wt + 2304*WSTR
                const float* __restrict__ bias,
                float* __restrict__ out)
{
    __shared__ _Float16 Wl[DD * WSTR];
    __shared__ _Float16 Al[SLAB * WSTR];
    const int tid  = threadIdx.x;
    const int wv   = tid >> 6;
    const int lane = tid & 63;
    const int l15  = lane & 15;
    const int quad = lane >> 4;

    for (int u = tid; u < (DD * WSTR) / 8; u += 256)
        *(v8h*)(Wl + (size_t)u * 8) = *(const v8h*)(Wt + (size_t)u * 8);

    float4 bf[2];
    #pragma unroll
    for (int ct = 0; ct < 2; ++ct)
        bf[ct] = *(const float4*)(bias + wv * 32 + ct * 16 + quad * 4);

    for (int s = blockIdx.x; s < NSLAB; s += gridDim.x) {
        __syncthreads();
        #pragma unroll
        for (int j = 0; j < 2; ++j) {
            int u = tid + j * 256;
            int row = u >> 4, c8 = (u & 15) * 8;
            v8h g = *(const v8h*)(oa + ((size_t)s * SLAB + row) * DD + c8);
            v8h o;
            #pragma unroll
            for (int q = 0; q < 8; ++q)
                o[q] = (_Float16)gelu_exact((float)g[q]);
            *(v8h*)(Al + row * WSTR + c8) = o;
        }
        __syncthreads();

        v4f acc[2][2];
        #pragma unroll
        for (int ct = 0; ct < 2; ++ct)
            #pragma unroll
            for (int rt = 0; rt < 2; ++rt)
                acc[ct][rt] = (v4f){0.f, 0.f, 0.f, 0.f};

        #pragma unroll
        for (int ks = 0; ks < 4; ++ks) {
            v8h xf0 = *(v8h*)(Al + l15 * WSTR + ks * 32 + quad * 8);
            v8h xf1 = *(v8h*)(Al + (16 + l15) * WSTR + ks * 32 + quad * 8);
            v8h wf[2];
            #pragma unroll
            for (int ct = 0; ct < 2; ++ct)
                wf[ct] = *(v8h*)(Wl + (wv * 32 + ct * 16 + l15) * WSTR + ks * 32 + quad * 8);
            #pragma unroll
            for (int ct = 0; ct < 2; ++ct) {
                acc[ct][0] = __builtin_amdgcn_mfma_f32_16x16x32_f16(wf[ct], xf0, acc[ct][0], 0, 0, 0);
                acc[ct][1] = __builtin_amdgcn_mfma_f32_16x16x32_f16(wf[ct], xf1, acc[ct][1], 0, 0, 0);
            }
        }

        #pragma unroll
        for (int ct = 0; ct < 2; ++ct)
            #pragma unroll
            for (int rt = 0; rt < 2; ++rt) {
                const size_t row = (size_t)s * SLAB + rt * 16 + l15;
                const int c0 = wv * 32 + ct * 16 + quad * 4;
                float4 o;
                o.x = acc[ct][rt][0] + bf[ct].x;
                o.y = acc[ct][rt][1] + bf[ct].y;
                o.z = acc[ct][rt][2] + bf[ct].z;
                o.w = acc[ct][rt][3] + bf[ct].w;
                *(float4*)(out + row * DD + c0) = o;
            }
    }
}

extern "C" void kernel_launch(void* const* d_in, const int* in_sizes, int n_in,
                              void* d_out, int out_size, void* d_ws, size_t ws_size,
                              hipStream_t stream)
{
    const float* x           = (const float*)d_in[0];
    const int*   ei          = (const int*)d_in[1];
    const int*   et          = (const int*)d_in[2];
    const float* lin_skip_w  = (const float*)d_in[3];
    const float* film_skip_w = (const float*)d_in[4];
    const float* lins_w      = (const float*)d_in[5];
    const float* films_w     = (const float*)d_in[6];
    const float* films_b     = (const float*)d_in[7];
    const float* linear1_w   = (const float*)d_in[8];
    const float* linear1_b   = (const float*)d_in[9];
    float* out = (float*)d_out;
    char*  ws  = (char*)d_ws;

    // workspace layout (bytes, 256-aligned) — ~139 MB total
    _Float16* xh      = (_Float16*)(ws);                   // 25,600,000
    _Float16* wt      = (_Float16*)(ws + 25600000);        //    661,504
    _Float16* xl      = (_Float16*)(ws + 26261504);        // 25,600,000
    _Float16* bh      = (_Float16*)(ws + 51861504);        // 25,600,000
    _Float16* gh      = (_Float16*)(ws + 77461504);        // 25,600,000
    _Float16* oa      = (_Float16*)(ws + 103061504);       // 25,600,000
    int*      cnt     = (int*)     (ws + 128661504);       //  2,000,000
    int*      partial = (int*)     (ws + 130661504);       //  2,000,000
    int*      rowptr  = (int*)     (ws + 132661504);       //  2,000,128
    int*      head    = (int*)     (ws + 134661632);       //  2,000,000
    int*      srcs    = (int*)     (ws + 136661632);       //  2,400,000
    int*      bsum    = (int*)     (ws + 139061632);       //      4,096
    int*      bsum2   = (int*)     (ws + 139065728);       //      4,096

    prep<<<CONV_BLKS + ZERO_BLKS + TW_BLKS, 256, 0, stream>>>(
        x, xh, cnt, lin_skip_w, film_skip_w, lins_w, films_w, linear1_w, wt);

    // counting sort of edges by (rel, dst)
    count_kernel<<<(EE + 255) / 256, 256, 0, stream>>>(ei, et, cnt);
    scan1<<<NB1, 256, 0, stream>>>(cnt, partial, bsum);
    scan2<<<1, 512, 0, stream>>>(bsum, bsum2);
    scan3<<<NB1, 256, 0, stream>>>(partial, bsum2, rowptr, head);
    scatter_kernel<<<(EE + 255) / 256, 256, 0, stream>>>(ei, et, head, srcs);

    // skip path -> oa (f16)
    skip_mfma<<<512, 256, 0, stream>>>(xh, wt, oa);

    for (int r = 0; r < RR; ++r) {
        film_mfma<<<512, 256, 0, stream>>>(
            xh, wt + (size_t)(r + 1) * 384 * WSTR,
            films_b + (size_t)r * 2 * DD, xl, bh, gh);
        agg_pass<<<(NN + 15) / 16, 256, 0, stream>>>(
            rowptr + (size_t)r * NN, srcs, xl, bh, gh, oa);
    }

    final_mfma<<<512, 256, 0, stream>>>(oa, wt + (size_t)2304 * WSTR,
                                        linear1_b, out);
}